// Round 12
// baseline (1763.789 us; speedup 1.0000x reference)
//
#include <hip/hip_runtime.h>
#include <hip/hip_bf16.h>
#include <math.h>

#define B_SZ 4
#define C_SZ 512
#define N_SZ 4096
#define D_SZ 64
#define SHIFT 60.0f

typedef __attribute__((ext_vector_type(4))) float f32x4;
typedef __attribute__((ext_vector_type(8))) short bf16x8;
typedef __attribute__((ext_vector_type(8))) _Float16 f16x8;

// fp32 -> bf16 RNE via native convert
__device__ __forceinline__ short f2bf(float x) {
    return (short)__bfloat16_as_ushort(__float2bfloat16(x));
}

__device__ __forceinline__ bf16x8 pack8(float4 a, float4 b) {
    bf16x8 r;
    r[0] = f2bf(a.x); r[1] = f2bf(a.y); r[2] = f2bf(a.z); r[3] = f2bf(a.w);
    r[4] = f2bf(b.x); r[5] = f2bf(b.y); r[6] = f2bf(b.z); r[7] = f2bf(b.w);
    return r;
}

// fp32x8 -> fp16x8 (RNE)
__device__ __forceinline__ f16x8 pack8h(float4 a, float4 b) {
    f16x8 r;
    r[0] = (_Float16)a.x; r[1] = (_Float16)a.y; r[2] = (_Float16)a.z; r[3] = (_Float16)a.w;
    r[4] = (_Float16)b.x; r[5] = (_Float16)b.y; r[6] = (_Float16)b.z; r[7] = (_Float16)b.w;
    return r;
}

// ---------------------------------------------------------------------------
// Pre-pass: a fp32 -> bf16 (PV operand)
// ---------------------------------------------------------------------------
__global__ __launch_bounds__(256) void conv_a_kernel(
    const float* __restrict__ amat, short* __restrict__ abf)
{
    size_t i = ((size_t)blockIdx.x * 256 + threadIdx.x) * 8;
    float4 a0 = ((const float4*)(amat + i))[0];
    float4 a1 = ((const float4*)(amat + i))[1];
    *(bf16x8*)(abf + i) = pack8(a0, a1);
}

// Pre-pass: c fp32 -> fp16 (QK operand)
__global__ __launch_bounds__(256) void conv_c_kernel(
    const float* __restrict__ cmat, _Float16* __restrict__ ch)
{
    size_t i = ((size_t)blockIdx.x * 256 + threadIdx.x) * 8;
    float4 c0 = ((const float4*)(cmat + i))[0];
    float4 c1 = ((const float4*)(cmat + i))[1];
    *(f16x8*)(ch + i) = pack8h(c0, c1);
}

// ---------------------------------------------------------------------------
// Fused pass (pv6): R11 structure (4 waves, 256ch x 64m, fp16 QK, bf16 P in
// LDS 4-buffered, shift-softmax, L per-lane sums) + REGISTER PREFETCH:
//   - af (PV A-operand) double-buffered one chunk ahead in regs (64 VGPR)
//   - K fp16 fragments double-buffered one segment ahead (32 VGPR)
//   loads issued a full compute phase before use -> L2 latency hidden.
//   VGPR headroom: 2 waves/SIMD allows 256.
// ---------------------------------------------------------------------------
__global__ __launch_bounds__(256, 2) void pv6_kernel(
    const float* __restrict__ amat, const float* __restrict__ bmat,
    const short* __restrict__ abf, const _Float16* __restrict__ chm,
    float* __restrict__ out)
{
    const int t = threadIdx.x;
    const int lane = t & 63;
    const int l15 = lane & 15;
    const int lg = lane >> 4;
    const int w = t >> 6;

    const int bid = blockIdx.x;
    const int slice = bid & 7;         // -> XCD via dispatch round-robin
    const int gm0 = (bid >> 3) * 64;   // m-tile
    const int gc0 = (slice & 1) * 256; // ch half
    const int bz = slice >> 1;         // batch

    __shared__ __align__(16) short smp[4][64 * 72];  // P [m][n], 4 buffers
    __shared__ float ldsL4[4][64];

    // Q fragments (fp32 -> fp16 in regs, once per block)
    f16x8 qf[4][2];
#pragma unroll
    for (int mf = 0; mf < 4; ++mf)
#pragma unroll
        for (int kf = 0; kf < 2; ++kf) {
            const float* qp = bmat + ((size_t)bz * N_SZ + gm0 + mf * 16 + l15) * D_SZ
                              + kf * 32 + lg * 8;
            float4 q0 = ((const float4*)qp)[0];
            float4 q1 = ((const float4*)qp)[1];
            qf[mf][kf] = pack8h(q0, q1);
        }

    f32x4 acc[4][4];
#pragma unroll
    for (int i = 0; i < 4; ++i)
#pragma unroll
        for (int j = 0; j < 4; ++j)
            acc[i][j] = (f32x4){0.f, 0.f, 0.f, 0.f};

    float psum[4][4];
#pragma unroll
    for (int i = 0; i < 4; ++i)
#pragma unroll
        for (int j = 0; j < 4; ++j) psum[i][j] = 0.0f;

    // K-fragment base: c row (w*16 + l15), d-octet lg*8
    const _Float16* kb = chm + ((size_t)bz * N_SZ + w * 16 + l15) * D_SZ + lg * 8;
    // A-fragment base: a row (gc0 + w*64 + l15), n-octet lg*8
    const short* ab = abf + ((size_t)bz * C_SZ + gc0 + w * 64 + l15) * N_SZ + lg * 8;

    // prefetch registers
    bf16x8 afr[2][4][2];   // [buf][chf][kf] for one 64-n chunk
    f16x8 krr[2][2][2];    // [set][chunk-in-segment][half]

    auto LOADAF = [&](int n0, int buf) {
#pragma unroll
        for (int chf = 0; chf < 4; ++chf)
#pragma unroll
            for (int kf = 0; kf < 2; ++kf)
                afr[buf][chf][kf] =
                    *(const bf16x8*)(ab + (size_t)chf * 16 * N_SZ + n0 + kf * 32);
    };
    auto LOADK = [&](int n0, int set) {
#pragma unroll
        for (int ck = 0; ck < 2; ++ck) {
            const _Float16* kp = kb + (size_t)(n0 + ck * 64) * D_SZ;
            krr[set][ck][0] = *(const f16x8*)(kp);
            krr[set][ck][1] = *(const f16x8*)(kp + 32);
        }
    };

    // QK for chunk n0 (K from regs) -> P into smp[pbuf]; per-lane row sums
    auto QK = [&](int pbuf, f16x8 k0, f16x8 k1) {
#pragma unroll
        for (int mf = 0; mf < 4; ++mf) {
            f32x4 s = {0.f, 0.f, 0.f, 0.f};
            s = __builtin_amdgcn_mfma_f32_16x16x32_f16(qf[mf][0], k0, s, 0, 0, 0);
            s = __builtin_amdgcn_mfma_f32_16x16x32_f16(qf[mf][1], k1, s, 0, 0, 0);
#pragma unroll
            for (int r = 0; r < 4; ++r) {
                float p = __expf(s[r] - SHIFT);
                psum[mf][r] += p;
                smp[pbuf][(mf * 16 + lg * 4 + r) * 72 + w * 16 + l15] = f2bf(p);
            }
        }
    };

    // PV for chunk (af from regs buf) reading smp[pbuf]
    auto PV = [&](int pbuf, int buf) {
#pragma unroll
        for (int kf = 0; kf < 2; ++kf) {
            bf16x8 pf[4];
#pragma unroll
            for (int mf = 0; mf < 4; ++mf)
                pf[mf] = *(const bf16x8*)&smp[pbuf][(mf * 16 + l15) * 72 + kf * 32 + lg * 8];
#pragma unroll
            for (int chf = 0; chf < 4; ++chf)
#pragma unroll
                for (int mf = 0; mf < 4; ++mf)
                    acc[chf][mf] = __builtin_amdgcn_mfma_f32_16x16x32_bf16(
                        afr[buf][chf][kf], pf[mf], acc[chf][mf], 0, 0, 0);
        }
    };

    // prologue
    LOADK(0, 0);                           // chunks 0,1 -> set 0
    QK(0, krr[0][0][0], krr[0][0][1]);     // chunk 0 -> pbuf 0
    QK(1, krr[0][1][0], krr[0][1][1]);     // chunk 1 -> pbuf 1
    LOADK(128, 1);                         // chunks 2,3 -> set 1
    LOADAF(0, 0);                          // chunk 0 -> afr[0]

    for (int s = 0; s < 31; ++s) {
        __syncthreads();
        LOADAF(s * 128 + 64, 1);           // chunk 2s+1
        PV((2 * s) & 3, 0);
        LOADAF(s * 128 + 128, 0);          // chunk 2s+2 (next segment)
        PV((2 * s + 1) & 3, 1);
        const int set = (s + 1) & 1;
        QK((2 * s + 2) & 3, krr[set][0][0], krr[set][0][1]);
        QK((2 * s + 3) & 3, krr[set][1][0], krr[set][1][1]);
        LOADK(s < 30 ? s * 128 + 256 : 0, s & 1);  // chunks 2s+4,2s+5 (dead @s=30)
    }
    __syncthreads();
    LOADAF(4032, 1);                       // chunk 63
    PV(2, 0);                              // chunk 62 (afr[0] loaded @s=30)
    PV(3, 1);                              // chunk 63

    // L reduction: butterfly over the 16 l15 lanes, then cross-wave via LDS.
#pragma unroll
    for (int mf = 0; mf < 4; ++mf)
#pragma unroll
        for (int r = 0; r < 4; ++r) {
            float v = psum[mf][r];
            v += __shfl_xor(v, 1, 64);
            v += __shfl_xor(v, 2, 64);
            v += __shfl_xor(v, 4, 64);
            v += __shfl_xor(v, 8, 64);
            if (l15 == 0) ldsL4[w][mf * 16 + lg * 4 + r] = v;
        }
    __syncthreads();

    float ri[4];
#pragma unroll
    for (int mf = 0; mf < 4; ++mf) {
        int m = mf * 16 + l15;
        ri[mf] = 1.0f / (ldsL4[0][m] + ldsL4[1][m] + ldsL4[2][m] + ldsL4[3][m]);
    }

    // epilogue: out = acc / L + a
#pragma unroll
    for (int chf = 0; chf < 4; ++chf)
#pragma unroll
        for (int mf = 0; mf < 4; ++mf) {
            const int m = gm0 + mf * 16 + l15;
#pragma unroll
            for (int r = 0; r < 4; ++r) {
                const int ch = gc0 + w * 64 + chf * 16 + lg * 4 + r;
                size_t o = ((size_t)bz * C_SZ + ch) * N_SZ + m;
                out[o] = acc[chf][mf][r] * ri[mf] + amat[o];
            }
        }
}

extern "C" void kernel_launch(void* const* d_in, const int* in_sizes, int n_in,
                              void* d_out, int out_size, void* d_ws, size_t ws_size,
                              hipStream_t stream) {
    const float* a = (const float*)d_in[0];
    const float* b = (const float*)d_in[1];
    const float* c = (const float*)d_in[2];
    float* out = (float*)d_out;

    // ws layout: abf (bf16, 8 MB) | c fp16 (2 MB)
    const size_t abf_b = (size_t)B_SZ * C_SZ * N_SZ * 2;

    short* abf = (short*)d_ws;
    _Float16* chm = (_Float16*)((char*)d_ws + abf_b);

    conv_a_kernel<<<dim3((B_SZ * C_SZ * N_SZ) / (256 * 8)), 256, 0, stream>>>(a, abf);
    conv_c_kernel<<<dim3((B_SZ * N_SZ * D_SZ) / (256 * 8)), 256, 0, stream>>>(c, chm);
    pv6_kernel<<<dim3(512), 256, 0, stream>>>(a, b, abf, chm, out);
}

// Round 13
// 188.484 us; speedup vs baseline: 9.3577x; 9.3577x over previous
//
#include <hip/hip_runtime.h>
#include <hip/hip_bf16.h>
#include <math.h>

#define B_SZ 4
#define C_SZ 512
#define N_SZ 4096
#define D_SZ 64
#define SHIFT 60.0f

typedef __attribute__((ext_vector_type(4))) float f32x4;
typedef __attribute__((ext_vector_type(8))) short bf16x8;
typedef __attribute__((ext_vector_type(8))) _Float16 f16x8;

// fp32 -> bf16 RNE via native convert
__device__ __forceinline__ short f2bf(float x) {
    return (short)__bfloat16_as_ushort(__float2bfloat16(x));
}

__device__ __forceinline__ bf16x8 pack8(float4 a, float4 b) {
    bf16x8 r;
    r[0] = f2bf(a.x); r[1] = f2bf(a.y); r[2] = f2bf(a.z); r[3] = f2bf(a.w);
    r[4] = f2bf(b.x); r[5] = f2bf(b.y); r[6] = f2bf(b.z); r[7] = f2bf(b.w);
    return r;
}

// fp32x8 -> fp16x8 (RNE)
__device__ __forceinline__ f16x8 pack8h(float4 a, float4 b) {
    f16x8 r;
    r[0] = (_Float16)a.x; r[1] = (_Float16)a.y; r[2] = (_Float16)a.z; r[3] = (_Float16)a.w;
    r[4] = (_Float16)b.x; r[5] = (_Float16)b.y; r[6] = (_Float16)b.z; r[7] = (_Float16)b.w;
    return r;
}

// ---------------------------------------------------------------------------
// Pre-pass: a fp32 -> bf16 (PV operand)
// ---------------------------------------------------------------------------
__global__ __launch_bounds__(256) void conv_a_kernel(
    const float* __restrict__ amat, short* __restrict__ abf)
{
    size_t i = ((size_t)blockIdx.x * 256 + threadIdx.x) * 8;
    float4 a0 = ((const float4*)(amat + i))[0];
    float4 a1 = ((const float4*)(amat + i))[1];
    *(bf16x8*)(abf + i) = pack8(a0, a1);
}

// Pre-pass: c fp32 -> fp16 (QK operand)
__global__ __launch_bounds__(256) void conv_c_kernel(
    const float* __restrict__ cmat, _Float16* __restrict__ ch)
{
    size_t i = ((size_t)blockIdx.x * 256 + threadIdx.x) * 8;
    float4 c0 = ((const float4*)(cmat + i))[0];
    float4 c1 = ((const float4*)(cmat + i))[1];
    *(f16x8*)(ch + i) = pack8h(c0, c1);
}

// ---------------------------------------------------------------------------
// Fused pass (pv7): R11 structure + register prefetch with STATIC buffer
// naming (R12's runtime-indexed krr[set] spilled to scratch -> 10x slower).
// All reg buffers are named arrays passed by reference; the segment loop is
// unrolled x2 so buffer selection is compile-time. LDS pbuf stays runtime.
// ---------------------------------------------------------------------------
__global__ __launch_bounds__(256, 2) void pv7_kernel(
    const float* __restrict__ amat, const float* __restrict__ bmat,
    const short* __restrict__ abf, const _Float16* __restrict__ chm,
    float* __restrict__ out)
{
    const int t = threadIdx.x;
    const int lane = t & 63;
    const int l15 = lane & 15;
    const int lg = lane >> 4;
    const int w = t >> 6;

    const int bid = blockIdx.x;
    const int slice = bid & 7;         // -> XCD via dispatch round-robin
    const int gm0 = (bid >> 3) * 64;   // m-tile
    const int gc0 = (slice & 1) * 256; // ch half
    const int bz = slice >> 1;         // batch

    __shared__ __align__(16) short smp[4][64 * 72];  // P [m][n], 4 buffers
    __shared__ float ldsL4[4][64];

    // Q fragments (fp32 -> fp16 in regs, once per block)
    f16x8 qf[4][2];
#pragma unroll
    for (int mf = 0; mf < 4; ++mf)
#pragma unroll
        for (int kf = 0; kf < 2; ++kf) {
            const float* qp = bmat + ((size_t)bz * N_SZ + gm0 + mf * 16 + l15) * D_SZ
                              + kf * 32 + lg * 8;
            float4 q0 = ((const float4*)qp)[0];
            float4 q1 = ((const float4*)qp)[1];
            qf[mf][kf] = pack8h(q0, q1);
        }

    f32x4 acc[4][4];
#pragma unroll
    for (int i = 0; i < 4; ++i)
#pragma unroll
        for (int j = 0; j < 4; ++j)
            acc[i][j] = (f32x4){0.f, 0.f, 0.f, 0.f};

    float psum[4][4];
#pragma unroll
    for (int i = 0; i < 4; ++i)
#pragma unroll
        for (int j = 0; j < 4; ++j) psum[i][j] = 0.0f;

    // K-fragment base: c row (w*16 + l15), d-octet lg*8
    const _Float16* kb = chm + ((size_t)bz * N_SZ + w * 16 + l15) * D_SZ + lg * 8;
    // A-fragment base: a row (gc0 + w*64 + l15), n-octet lg*8
    const short* ab = abf + ((size_t)bz * C_SZ + gc0 + w * 64 + l15) * N_SZ + lg * 8;

    // prefetch registers: NAMED buffers only (no runtime indexing!)
    bf16x8 afr0[4][2], afr1[4][2];   // [chf][kf], one 64-n chunk each
    f16x8 krr0[2][2], krr1[2][2];    // [chunk-in-segment][half]

    auto LOADAF = [&](int n0, bf16x8 (&dst)[4][2]) {
#pragma unroll
        for (int chf = 0; chf < 4; ++chf)
#pragma unroll
            for (int kf = 0; kf < 2; ++kf)
                dst[chf][kf] =
                    *(const bf16x8*)(ab + (size_t)chf * 16 * N_SZ + n0 + kf * 32);
    };
    auto LOADK = [&](int n0, f16x8 (&dst)[2][2]) {
#pragma unroll
        for (int ck = 0; ck < 2; ++ck) {
            const _Float16* kp = kb + (size_t)(n0 + ck * 64) * D_SZ;
            dst[ck][0] = *(const f16x8*)(kp);
            dst[ck][1] = *(const f16x8*)(kp + 32);
        }
    };

    // QK: K from regs -> P into smp[pbuf]; per-lane row sums
    auto QK = [&](int pbuf, f16x8 k0, f16x8 k1) {
#pragma unroll
        for (int mf = 0; mf < 4; ++mf) {
            f32x4 s = {0.f, 0.f, 0.f, 0.f};
            s = __builtin_amdgcn_mfma_f32_16x16x32_f16(qf[mf][0], k0, s, 0, 0, 0);
            s = __builtin_amdgcn_mfma_f32_16x16x32_f16(qf[mf][1], k1, s, 0, 0, 0);
#pragma unroll
            for (int r = 0; r < 4; ++r) {
                float p = __expf(s[r] - SHIFT);
                psum[mf][r] += p;
                smp[pbuf][(mf * 16 + lg * 4 + r) * 72 + w * 16 + l15] = f2bf(p);
            }
        }
    };

    // PV: af from named reg buffer, P from smp[pbuf]
    auto PV = [&](int pbuf, bf16x8 (&af)[4][2]) {
#pragma unroll
        for (int kf = 0; kf < 2; ++kf) {
            bf16x8 pf[4];
#pragma unroll
            for (int mf = 0; mf < 4; ++mf)
                pf[mf] = *(const bf16x8*)&smp[pbuf][(mf * 16 + l15) * 72 + kf * 32 + lg * 8];
#pragma unroll
            for (int chf = 0; chf < 4; ++chf)
#pragma unroll
                for (int mf = 0; mf < 4; ++mf)
                    acc[chf][mf] = __builtin_amdgcn_mfma_f32_16x16x32_bf16(
                        af[chf][kf], pf[mf], acc[chf][mf], 0, 0, 0);
        }
    };

    // one segment: PV chunks 2s,2s+1; QK chunks 2s+2,2s+3 (K in kq);
    // prefetch K for chunks 2s+4,2s+5 into kn (unless last).
    auto SEG = [&](int s, f16x8 (&kq)[2][2], f16x8 (&kn)[2][2],
                   int p0, int p1, int p2, int p3, bool loadk) {
        __syncthreads();
        LOADAF(s * 128 + 64, afr1);
        PV(p0, afr0);
        LOADAF(s * 128 + 128, afr0);
        PV(p1, afr1);
        QK(p2, kq[0][0], kq[0][1]);
        QK(p3, kq[1][0], kq[1][1]);
        if (loadk) LOADK(s * 128 + 256, kn);
    };

    // prologue
    LOADK(0, krr0);                        // chunks 0,1
    QK(0, krr0[0][0], krr0[0][1]);         // chunk 0 -> pbuf 0
    QK(1, krr0[1][0], krr0[1][1]);         // chunk 1 -> pbuf 1
    LOADK(128, krr1);                      // chunks 2,3
    LOADAF(0, afr0);                       // chunk 0

    for (int sp = 0; sp < 15; ++sp) {
        const int s = 2 * sp;
        SEG(s,     krr1, krr0, 0, 1, 2, 3, true);   // even s
        SEG(s + 1, krr0, krr1, 2, 3, 0, 1, true);   // odd s
    }
    SEG(30, krr1, krr0, 0, 1, 2, 3, false);

    __syncthreads();
    LOADAF(4032, afr1);                    // chunk 63
    PV(2, afr0);                           // chunk 62
    PV(3, afr1);                           // chunk 63

    // L reduction: butterfly over the 16 l15 lanes, then cross-wave via LDS.
#pragma unroll
    for (int mf = 0; mf < 4; ++mf)
#pragma unroll
        for (int r = 0; r < 4; ++r) {
            float v = psum[mf][r];
            v += __shfl_xor(v, 1, 64);
            v += __shfl_xor(v, 2, 64);
            v += __shfl_xor(v, 4, 64);
            v += __shfl_xor(v, 8, 64);
            if (l15 == 0) ldsL4[w][mf * 16 + lg * 4 + r] = v;
        }
    __syncthreads();

    float ri[4];
#pragma unroll
    for (int mf = 0; mf < 4; ++mf) {
        int m = mf * 16 + l15;
        ri[mf] = 1.0f / (ldsL4[0][m] + ldsL4[1][m] + ldsL4[2][m] + ldsL4[3][m]);
    }

    // epilogue: out = acc / L + a
#pragma unroll
    for (int chf = 0; chf < 4; ++chf)
#pragma unroll
        for (int mf = 0; mf < 4; ++mf) {
            const int m = gm0 + mf * 16 + l15;
#pragma unroll
            for (int r = 0; r < 4; ++r) {
                const int ch = gc0 + w * 64 + chf * 16 + lg * 4 + r;
                size_t o = ((size_t)bz * C_SZ + ch) * N_SZ + m;
                out[o] = acc[chf][mf][r] * ri[mf] + amat[o];
            }
        }
}

extern "C" void kernel_launch(void* const* d_in, const int* in_sizes, int n_in,
                              void* d_out, int out_size, void* d_ws, size_t ws_size,
                              hipStream_t stream) {
    const float* a = (const float*)d_in[0];
    const float* b = (const float*)d_in[1];
    const float* c = (const float*)d_in[2];
    float* out = (float*)d_out;

    // ws layout: abf (bf16, 8 MB) | c fp16 (2 MB)
    const size_t abf_b = (size_t)B_SZ * C_SZ * N_SZ * 2;

    short* abf = (short*)d_ws;
    _Float16* chm = (_Float16*)((char*)d_ws + abf_b);

    conv_a_kernel<<<dim3((B_SZ * C_SZ * N_SZ) / (256 * 8)), 256, 0, stream>>>(a, abf);
    conv_c_kernel<<<dim3((B_SZ * N_SZ * D_SZ) / (256 * 8)), 256, 0, stream>>>(c, chm);
    pv7_kernel<<<dim3(512), 256, 0, stream>>>(a, b, abf, chm, out);
}